// Round 1
// 388.095 us; speedup vs baseline: 1.0023x; 1.0023x over previous
//
#include <hip/hip_runtime.h>
#include <math.h>

#define T_LEN  65536
#define TPB    256
#define VECS   (T_LEN / 4)       // 16384 float4 per row
#define VPT    (VECS / TPB)      // 64 vectors per thread
#define NSUPER (VPT / 4)         // 16 super-iterations of 4 independent loads
#define NWAVES (TPB / 64)        // 4
#define NB     (VECS / 64)       // 256 lane-0 boundary slots per row
#define EPS    1e-8f

struct Acc {
    float s1, s2, s3, s4, sa, ss, mx, mn;
    int zc;
};

// Branch-free pass-1 body: no global gather, no divergent load. Lane-0's
// cross-wave boundary pair is excluded here and added in the epilogue from
// LDS-stashed values.
__device__ __forceinline__ void p1_body(const float4& v, int lane, Acc& a) {
    float prev = __shfl_up(v.w, 1);
    if (lane == 0) prev = v.x;          // folds to one v_cndmask; counts nothing
    bool sp = prev < 0.f;
    bool b0 = v.x < 0.f, b1 = v.y < 0.f, b2 = v.z < 0.f, b3 = v.w < 0.f;
    a.zc += (int)(sp != b0) + (int)(b0 != b1) + (int)(b1 != b2) + (int)(b2 != b3);

    float e0 = v.x, e1 = v.y, e2 = v.z, e3 = v.w;
    a.s1 += e0 + e1 + e2 + e3;
    a.s2 = fmaf(e0, e0, a.s2); a.s2 = fmaf(e1, e1, a.s2);
    a.s2 = fmaf(e2, e2, a.s2); a.s2 = fmaf(e3, e3, a.s2);
    a.s3 = fmaf(e0 * e0, e0, a.s3); a.s3 = fmaf(e1 * e1, e1, a.s3);
    a.s3 = fmaf(e2 * e2, e2, a.s3); a.s3 = fmaf(e3 * e3, e3, a.s3);
    a.s4 = fmaf(e0 * e0, e0 * e0, a.s4); a.s4 = fmaf(e1 * e1, e1 * e1, a.s4);
    a.s4 = fmaf(e2 * e2, e2 * e2, a.s4); a.s4 = fmaf(e3 * e3, e3 * e3, a.s4);
    float a0 = fabsf(e0), a1 = fabsf(e1), a2 = fabsf(e2), a3 = fabsf(e3);
    a.sa += a0 + a1 + a2 + a3;
    // raw v_sqrt_f32 (1 ulp) instead of correctly-rounded libm expansion
    a.ss += __builtin_amdgcn_sqrtf(a0) + __builtin_amdgcn_sqrtf(a1)
          + __builtin_amdgcn_sqrtf(a2) + __builtin_amdgcn_sqrtf(a3);
    a.mx = fmaxf(fmaxf(a.mx, e0), fmaxf(e1, fmaxf(e2, e3)));
    a.mn = fminf(fminf(a.mn, e0), fminf(e1, fminf(e2, e3)));
}

__device__ __forceinline__ void p2_body(const float4& v, int lane, float m, int& mc) {
    float prev = __shfl_up(v.w, 1);
    if (lane == 0) prev = v.x;
    bool sp = prev < m;
    bool b0 = v.x < m, b1 = v.y < m, b2 = v.z < m, b3 = v.w < m;
    mc += (int)(sp != b0) + (int)(b0 != b1) + (int)(b1 != b2) + (int)(b2 != b3);
}

// One block per row, two passes (pass 2 = mean-crossing, L3-resident).
// MLP via 4 independent named float4 loads per super-iteration (no arrays —
// round-3 lesson: runtime-indexed arrays => scratch spills).
// New this round: lane-0 boundary pairs (x[256k-1], x[256k]) are stashed in
// LDS during pass 1 and resolved once in the epilogue, removing 128 divergent
// exec-masked global loads (and their vmcnt stalls) per thread.
__global__ __launch_bounds__(TPB) void stat_feat_fused(const float* __restrict__ x,
                                                       float* __restrict__ out) {
    const int row  = blockIdx.x;
    const int tid  = threadIdx.x;
    const int lane = tid & 63;
    const int wave = tid >> 6;

    const float4* __restrict__ xv = (const float4*)(x + (size_t)row * T_LEN);

    __shared__ float l[9][NWAVES];
    __shared__ float s_mean;
    __shared__ float wlast[NB];    // v.w of vectors with (vi & 63)==63, slot vi>>6
    __shared__ float xfirst[NB];   // v.x of vectors with (vi & 63)==0,  slot vi>>6

    Acc a;
    a.s1 = a.s2 = a.s3 = a.s4 = a.sa = a.ss = 0.f;
    a.mx = -__builtin_inff();
    a.mn = __builtin_inff();
    a.zc = 0;

    for (int g = 0; g < NSUPER; ++g) {
        const int base = g * 4 * TPB + tid;
        const int ia = base, ib = base + TPB, ic = base + 2 * TPB, id = base + 3 * TPB;
        float4 va = xv[ia];      // 4 independent loads in flight
        float4 vb = xv[ib];
        float4 vc = xv[ic];
        float4 vd = xv[id];
        if (lane == 63) {        // stash boundary values (cheap masked ds_write)
            wlast[ia >> 6] = va.w; wlast[ib >> 6] = vb.w;
            wlast[ic >> 6] = vc.w; wlast[id >> 6] = vd.w;
        }
        if (lane == 0) {
            xfirst[ia >> 6] = va.x; xfirst[ib >> 6] = vb.x;
            xfirst[ic >> 6] = vc.x; xfirst[id >> 6] = vd.x;
        }
        p1_body(va, lane, a);
        p1_body(vb, lane, a);
        p1_body(vc, lane, a);
        p1_body(vd, lane, a);
    }

#pragma unroll
    for (int o = 32; o > 0; o >>= 1) {
        a.s1 += __shfl_down(a.s1, o);
        a.s2 += __shfl_down(a.s2, o);
        a.s3 += __shfl_down(a.s3, o);
        a.s4 += __shfl_down(a.s4, o);
        a.sa += __shfl_down(a.sa, o);
        a.ss += __shfl_down(a.ss, o);
        a.zc += __shfl_down(a.zc, o);
        a.mx = fmaxf(a.mx, __shfl_down(a.mx, o));
        a.mn = fminf(a.mn, __shfl_down(a.mn, o));
    }

    if (lane == 0) {
        l[0][wave] = a.s1; l[1][wave] = a.s2; l[2][wave] = a.s3; l[3][wave] = a.s4;
        l[4][wave] = a.sa; l[5][wave] = a.ss; l[6][wave] = a.mx; l[7][wave] = a.mn;
        l[8][wave] = (float)a.zc;
    }
    __syncthreads();

    float S1 = 0.f, S2 = 0.f, S3 = 0.f, S4 = 0.f, SA = 0.f, SS = 0.f, ZC = 0.f;
    float MX = -__builtin_inff(), MN = __builtin_inff();
    if (tid == 0) {
#pragma unroll
        for (int wv = 0; wv < NWAVES; wv++) {
            S1 += l[0][wv]; S2 += l[1][wv]; S3 += l[2][wv]; S4 += l[3][wv];
            SA += l[4][wv]; SS += l[5][wv];
            MX = fmaxf(MX, l[6][wv]); MN = fminf(MN, l[7][wv]);
            ZC += l[8][wv];
        }
        s_mean = S1 / (float)T_LEN;
    }
    __syncthreads();

    // ---------------- pass 2: mean-crossing (L3-resident re-read) ----------------
    const float m = s_mean;
    int mc = 0;
    for (int g = 0; g < NSUPER; ++g) {
        const int base = g * 4 * TPB + tid;
        const int ia = base, ib = base + TPB, ic = base + 2 * TPB, id = base + 3 * TPB;
        float4 va = xv[ia];
        float4 vb = xv[ib];
        float4 vc = xv[ic];
        float4 vd = xv[id];
        p2_body(va, lane, m, mc);
        p2_body(vb, lane, m, mc);
        p2_body(vc, lane, m, mc);
        p2_body(vd, lane, m, mc);
    }

    // lane-0 boundary pairs (x[256k-1], x[256k]), k = tid = 1..255, from LDS
    int mb = 0, zb = 0;
    if (tid > 0) {
        float wl = wlast[tid - 1];
        float xf = xfirst[tid];
        zb = (int)((wl < 0.f) != (xf < 0.f));
        mb = (int)((wl < m) != (xf < m));
    }

#pragma unroll
    for (int o = 32; o > 0; o >>= 1) {
        mc += __shfl_down(mc, o);
        mb += __shfl_down(mb, o);
        zb += __shfl_down(zb, o);
    }

    __syncthreads();
    if (lane == 0) {
        l[0][wave] = (float)mc;
        l[1][wave] = (float)mb;
        l[2][wave] = (float)zb;
    }
    __syncthreads();

    if (tid == 0) {
        float MC = 0.f, MB = 0.f, ZB = 0.f;
#pragma unroll
        for (int wv = 0; wv < NWAVES; wv++) {
            MC += l[0][wv]; MB += l[1][wv]; ZB += l[2][wv];
        }
        MC += MB;          // add deferred lane-0 boundary crossings
        ZC += ZB;

        const float Tf = (float)T_LEN;
        float mean = S1 / Tf;
        float sq_mean = S2 / Tf;
        float var = (S2 - S1 * S1 / Tf) / (Tf - 1.f);
        var = fmaxf(var, 0.f);
        float stdv = sqrtf(var);
        float rms = sqrtf(sq_mean);
        float peak = MX, peak_neg = MN;
        float ptp = peak - peak_neg;
        float abs_peak = fabsf(peak);
        float crest = abs_peak / (rms + EPS);
        float mean_abs = SA / Tf;
        float shape = rms / (mean_abs + EPS);
        float impulse = abs_peak / (mean_abs + EPS);
        float sqrt_mean = SS / Tf;
        float clearance = abs_peak / (sqrt_mean * sqrt_mean + EPS);
        float ex3 = S3 / Tf;
        float m3 = ex3 - 3.f * mean * sq_mean + 2.f * mean * mean * mean;
        float m4 = S4 / Tf - 4.f * mean * ex3 + 6.f * mean * mean * sq_mean
                   - 3.f * mean * mean * mean * mean;
        float skew = m3 / (stdv * stdv * stdv + EPS);
        float kurt = m4 / (stdv * stdv * stdv * stdv + EPS) - 3.f;
        float zcr = ZC / (Tf - 1.f);
        float mcr = MC / (Tf - 1.f);
        float margin = abs_peak / (sqrt_mean + EPS);

        float* o = out + (size_t)row * 17;
        o[0] = mean;   o[1] = stdv;     o[2] = var;        o[3] = rms;
        o[4] = peak;   o[5] = peak_neg; o[6] = ptp;        o[7] = crest;
        o[8] = shape;  o[9] = impulse;  o[10] = clearance; o[11] = skew;
        o[12] = kurt;  o[13] = zcr;     o[14] = mcr;       o[15] = margin;
        o[16] = S2;
    }
}

extern "C" void kernel_launch(void* const* d_in, const int* in_sizes, int n_in,
                              void* d_out, int out_size, void* d_ws, size_t ws_size,
                              hipStream_t stream) {
    const float* x = (const float*)d_in[0];
    float* out = (float*)d_out;
    const int rows = in_sizes[0] / T_LEN;   // 1024
    stat_feat_fused<<<dim3(rows), dim3(TPB), 0, stream>>>(x, out);
}

// Round 2
// 384.275 us; speedup vs baseline: 1.0123x; 1.0099x over previous
//
#include <hip/hip_runtime.h>
#include <math.h>

#define T_LEN  65536
#define TPB    256
#define VECS   (T_LEN / 4)       // 16384 float4 per row
#define VPT    (VECS / TPB)      // 64 vectors per thread
#define NSUPER (VPT / 4)         // 16 super-iterations of 4 independent loads
#define NWAVES (TPB / 64)        // 4
#define NB     (VECS / 64)       // 256 lane-boundary slots per row
#define EPS    1e-8f

// Mean-crossing candidate band. Row mean of 65536 iid N(0,1) has sd 1/256
// ~= 0.0039; max |mean| over 1024 rows ~= 0.015. B = 0.05 gives 3.3x margin.
// Pairs fully outside the band have crossing status independent of m; pairs
// touching the band (~7.8%) are stashed fp32-exact and resolved post-mean.
#define BANDB  0.05f
#define CAP    6144              // candidate capacity: ~5100 expected + 10 sd

struct Acc {
    float s1, s2, s3, s4, sa, ss, mx, mn;
    int zc, mcb;                 // zc: zero crossings; mcb: always-cross pairs
};

__device__ __forceinline__ void mc_pair(float p, float q, Acc& a,
                                        float2* __restrict__ cand,
                                        int* __restrict__ cnt) {
    float lo = fminf(p, q), hi = fmaxf(p, q);
    // crossing for level m:  lo < m && hi >= m
    if (lo < BANDB && hi >= -BANDB) {            // not trivially-never
        if (lo < -BANDB && hi >= BANDB) {        // crosses every |m| < B
            a.mcb++;
        } else {                                 // depends on exact m: stash
            int idx = atomicAdd(cnt, 1);
            if (idx < CAP) cand[idx] = make_float2(lo, hi);
        }
    }
}

__device__ __forceinline__ void p1_body(const float4& v, int lane, Acc& a,
                                        float2* __restrict__ cand,
                                        int* __restrict__ cnt) {
    float prev = __shfl_up(v.w, 1);
    if (lane == 0) prev = v.x;   // degenerate (x,x) pair: contributes 0 always
    bool sp = prev < 0.f;
    bool b0 = v.x < 0.f, b1 = v.y < 0.f, b2 = v.z < 0.f, b3 = v.w < 0.f;
    a.zc += (int)(sp != b0) + (int)(b0 != b1) + (int)(b1 != b2) + (int)(b2 != b3);

    // mean-crossing pair classification (replaces the whole pass 2)
    mc_pair(prev, v.x, a, cand, cnt);
    mc_pair(v.x, v.y, a, cand, cnt);
    mc_pair(v.y, v.z, a, cand, cnt);
    mc_pair(v.z, v.w, a, cand, cnt);

    float e0 = v.x, e1 = v.y, e2 = v.z, e3 = v.w;
    a.s1 += e0 + e1 + e2 + e3;
    a.s2 = fmaf(e0, e0, a.s2); a.s2 = fmaf(e1, e1, a.s2);
    a.s2 = fmaf(e2, e2, a.s2); a.s2 = fmaf(e3, e3, a.s2);
    a.s3 = fmaf(e0 * e0, e0, a.s3); a.s3 = fmaf(e1 * e1, e1, a.s3);
    a.s3 = fmaf(e2 * e2, e2, a.s3); a.s3 = fmaf(e3 * e3, e3, a.s3);
    a.s4 = fmaf(e0 * e0, e0 * e0, a.s4); a.s4 = fmaf(e1 * e1, e1 * e1, a.s4);
    a.s4 = fmaf(e2 * e2, e2 * e2, a.s4); a.s4 = fmaf(e3 * e3, e3 * e3, a.s4);
    float a0 = fabsf(e0), a1 = fabsf(e1), a2 = fabsf(e2), a3 = fabsf(e3);
    a.sa += a0 + a1 + a2 + a3;
    a.ss += __builtin_amdgcn_sqrtf(a0) + __builtin_amdgcn_sqrtf(a1)
          + __builtin_amdgcn_sqrtf(a2) + __builtin_amdgcn_sqrtf(a3);
    a.mx = fmaxf(fmaxf(a.mx, e0), fmaxf(e1, fmaxf(e2, e3)));
    a.mn = fminf(fminf(a.mn, e0), fminf(e1, fminf(e2, e3)));
}

// Fallback-only (candidate overflow, statistically never): global re-read.
__device__ __forceinline__ void p2_body(const float4& v, int lane, float m, int& mc) {
    float prev = __shfl_up(v.w, 1);
    if (lane == 0) prev = v.x;
    bool sp = prev < m;
    bool b0 = v.x < m, b1 = v.y < m, b2 = v.z < m, b3 = v.w < m;
    mc += (int)(sp != b0) + (int)(b0 != b1) + (int)(b1 != b2) + (int)(b2 != b3);
}

// One block per row, SINGLE data pass. Mean-crossing resolved from an
// LDS candidate list (pairs touching [-B, B]) after the mean is known —
// the former pass-2 L3 re-read (256 MiB, ~18 us) is gone.
__global__ __launch_bounds__(TPB) void stat_feat_fused(const float* __restrict__ x,
                                                       float* __restrict__ out) {
    const int row  = blockIdx.x;
    const int tid  = threadIdx.x;
    const int lane = tid & 63;
    const int wave = tid >> 6;

    const float4* __restrict__ xv = (const float4*)(x + (size_t)row * T_LEN);

    __shared__ float  l[10][NWAVES];
    __shared__ float  s_mean;
    __shared__ float  wlast[NB];   // v.w of vectors with (vi&63)==63, slot vi>>6
    __shared__ float  xfirst[NB];  // v.x of vectors with (vi&63)==0,  slot vi>>6
    __shared__ float2 cand[CAP];   // 48 KB candidate (min,max) pairs
    __shared__ int    s_cnt;

    if (tid == 0) s_cnt = 0;
    __syncthreads();

    Acc a;
    a.s1 = a.s2 = a.s3 = a.s4 = a.sa = a.ss = 0.f;
    a.mx = -__builtin_inff();
    a.mn = __builtin_inff();
    a.zc = 0; a.mcb = 0;

    for (int g = 0; g < NSUPER; ++g) {
        const int base = g * 4 * TPB + tid;
        const int ia = base, ib = base + TPB, ic = base + 2 * TPB, id = base + 3 * TPB;
        float4 va = xv[ia];      // 4 independent loads in flight
        float4 vb = xv[ib];
        float4 vc = xv[ic];
        float4 vd = xv[id];
        if (lane == 63) {        // stash wave-edge boundary values
            wlast[ia >> 6] = va.w; wlast[ib >> 6] = vb.w;
            wlast[ic >> 6] = vc.w; wlast[id >> 6] = vd.w;
        }
        if (lane == 0) {
            xfirst[ia >> 6] = va.x; xfirst[ib >> 6] = vb.x;
            xfirst[ic >> 6] = vc.x; xfirst[id >> 6] = vd.x;
        }
        p1_body(va, lane, a, cand, &s_cnt);
        p1_body(vb, lane, a, cand, &s_cnt);
        p1_body(vc, lane, a, cand, &s_cnt);
        p1_body(vd, lane, a, cand, &s_cnt);
    }

#pragma unroll
    for (int o = 32; o > 0; o >>= 1) {
        a.s1 += __shfl_down(a.s1, o);
        a.s2 += __shfl_down(a.s2, o);
        a.s3 += __shfl_down(a.s3, o);
        a.s4 += __shfl_down(a.s4, o);
        a.sa += __shfl_down(a.sa, o);
        a.ss += __shfl_down(a.ss, o);
        a.zc += __shfl_down(a.zc, o);
        a.mcb += __shfl_down(a.mcb, o);
        a.mx = fmaxf(a.mx, __shfl_down(a.mx, o));
        a.mn = fminf(a.mn, __shfl_down(a.mn, o));
    }

    if (lane == 0) {
        l[0][wave] = a.s1; l[1][wave] = a.s2; l[2][wave] = a.s3; l[3][wave] = a.s4;
        l[4][wave] = a.sa; l[5][wave] = a.ss; l[6][wave] = a.mx; l[7][wave] = a.mn;
        l[8][wave] = (float)a.zc; l[9][wave] = (float)a.mcb;
    }
    __syncthreads();

    float S1 = 0.f, S2 = 0.f, S3 = 0.f, S4 = 0.f, SA = 0.f, SS = 0.f;
    float ZC = 0.f, MCB = 0.f;
    float MX = -__builtin_inff(), MN = __builtin_inff();
    if (tid == 0) {
#pragma unroll
        for (int wv = 0; wv < NWAVES; wv++) {
            S1 += l[0][wv]; S2 += l[1][wv]; S3 += l[2][wv]; S4 += l[3][wv];
            SA += l[4][wv]; SS += l[5][wv];
            MX = fmaxf(MX, l[6][wv]); MN = fminf(MN, l[7][wv]);
            ZC += l[8][wv]; MCB += l[9][wv];
        }
        s_mean = S1 / (float)T_LEN;
    }
    __syncthreads();

    // ------------- resolve mean-crossings from the candidate list -------------
    const float m = s_mean;
    const int ncand = s_cnt;            // uniform after barrier
    int mcc = 0;
    if (ncand <= CAP) {
        for (int i = tid; i < ncand; i += TPB) {
            float2 c = cand[i];
            mcc += (int)((c.x < m) && (c.y >= m));
        }
    } else {
        // overflow fallback (never expected): exact global re-read
        for (int g = 0; g < NSUPER; ++g) {
            const int base = g * 4 * TPB + tid;
            const int ia = base, ib = base + TPB, ic = base + 2 * TPB, id = base + 3 * TPB;
            float4 va = xv[ia];
            float4 vb = xv[ib];
            float4 vc = xv[ic];
            float4 vd = xv[id];
            p2_body(va, lane, m, mcc);
            p2_body(vb, lane, m, mcc);
            p2_body(vc, lane, m, mcc);
            p2_body(vd, lane, m, mcc);
        }
    }

    // wave-edge boundary pairs (x[256k-1], x[256k]), exact fp32 from LDS
    int mb = 0, zb = 0;
    if (tid > 0) {
        float wl = wlast[tid - 1];
        float xf = xfirst[tid];
        zb = (int)((wl < 0.f) != (xf < 0.f));
        mb = (int)((wl < m) != (xf < m));
    }

#pragma unroll
    for (int o = 32; o > 0; o >>= 1) {
        mcc += __shfl_down(mcc, o);
        mb  += __shfl_down(mb, o);
        zb  += __shfl_down(zb, o);
    }

    __syncthreads();
    if (lane == 0) {
        l[0][wave] = (float)mcc;
        l[1][wave] = (float)mb;
        l[2][wave] = (float)zb;
    }
    __syncthreads();

    if (tid == 0) {
        float MC = 0.f, MB = 0.f, ZB = 0.f;
#pragma unroll
        for (int wv = 0; wv < NWAVES; wv++) {
            MC += l[0][wv]; MB += l[1][wv]; ZB += l[2][wv];
        }
        MC += MB;
        if (ncand <= CAP) MC += MCB;    // base count only in candidate path
        ZC += ZB;

        const float Tf = (float)T_LEN;
        float mean = S1 / Tf;
        float sq_mean = S2 / Tf;
        float var = (S2 - S1 * S1 / Tf) / (Tf - 1.f);
        var = fmaxf(var, 0.f);
        float stdv = sqrtf(var);
        float rms = sqrtf(sq_mean);
        float peak = MX, peak_neg = MN;
        float ptp = peak - peak_neg;
        float abs_peak = fabsf(peak);
        float crest = abs_peak / (rms + EPS);
        float mean_abs = SA / Tf;
        float shape = rms / (mean_abs + EPS);
        float impulse = abs_peak / (mean_abs + EPS);
        float sqrt_mean = SS / Tf;
        float clearance = abs_peak / (sqrt_mean * sqrt_mean + EPS);
        float ex3 = S3 / Tf;
        float m3 = ex3 - 3.f * mean * sq_mean + 2.f * mean * mean * mean;
        float m4 = S4 / Tf - 4.f * mean * ex3 + 6.f * mean * mean * sq_mean
                   - 3.f * mean * mean * mean * mean;
        float skew = m3 / (stdv * stdv * stdv + EPS);
        float kurt = m4 / (stdv * stdv * stdv * stdv + EPS) - 3.f;
        float zcr = ZC / (Tf - 1.f);
        float mcr = MC / (Tf - 1.f);
        float margin = abs_peak / (sqrt_mean + EPS);

        float* o = out + (size_t)row * 17;
        o[0] = mean;   o[1] = stdv;     o[2] = var;        o[3] = rms;
        o[4] = peak;   o[5] = peak_neg; o[6] = ptp;        o[7] = crest;
        o[8] = shape;  o[9] = impulse;  o[10] = clearance; o[11] = skew;
        o[12] = kurt;  o[13] = zcr;     o[14] = mcr;       o[15] = margin;
        o[16] = S2;
    }
}

extern "C" void kernel_launch(void* const* d_in, const int* in_sizes, int n_in,
                              void* d_out, int out_size, void* d_ws, size_t ws_size,
                              hipStream_t stream) {
    const float* x = (const float*)d_in[0];
    float* out = (float*)d_out;
    const int rows = in_sizes[0] / T_LEN;   // 1024
    stat_feat_fused<<<dim3(rows), dim3(TPB), 0, stream>>>(x, out);
}

// Round 3
// 381.145 us; speedup vs baseline: 1.0206x; 1.0082x over previous
//
#include <hip/hip_runtime.h>
#include <math.h>

#define T_LEN  65536
#define TPB    256
#define VECS   (T_LEN / 4)       // 16384 float4 per row
#define VPT    (VECS / TPB)      // 64 vectors per thread
#define NSUPER (VPT / 4)         // 16 super-iterations of 4 independent loads
#define NWAVES (TPB / 64)        // 4
#define NB     (VECS / 64)       // 256 lane-boundary slots per row
#define EPS    1e-8f

// Mean-crossing candidate band. Row mean of 65536 iid N(0,1) has sd 1/256;
// max |mean| over 1024 rows ~ 0.013. B = 0.05 is ~3.8x margin; if |mean|
// ever reaches B we take the exact global-re-read fallback, so correctness
// never depends on this bound.
#define BANDB  0.05f
#define WCAP   1536              // per-wave candidate slice (expected ~1275)

struct Acc {
    float s1, s2, s3, s4, sa, ss, mx, mn;
    int mcb;                     // pairs that cross EVERY level in (-B, B)
};

__device__ __forceinline__ int mbcnt64(unsigned long long m) {
    int c = __builtin_amdgcn_mbcnt_lo((unsigned)m, 0);
    return __builtin_amdgcn_mbcnt_hi((unsigned)(m >> 32), c);
}

// Classify one adjacent pair. never: crosses no level in (-B,B). always:
// crosses all of them (counted in mcb, serves both zc and mcr). Else stash
// (lo,hi) into this wave's private LDS slice via ballot compaction —
// no atomics, no DS-return stalls.
__device__ __forceinline__ void pair_cls(float p, float q, Acc& a,
                                         float2* __restrict__ mycand, int& wcnt) {
    float lo = fminf(p, q), hi = fmaxf(p, q);
    bool always = (lo < -BANDB) && (hi >= BANDB);
    bool never  = (lo >= BANDB) || (hi < -BANDB);
    a.mcb += (int)always;
    bool st = !(always || never);
    unsigned long long mask = __ballot(st);
    if (st) {
        int o = wcnt + mbcnt64(mask);
        if (o < WCAP) mycand[o] = make_float2(lo, hi);
    }
    wcnt += __builtin_popcountll(mask);
}

__device__ __forceinline__ void p1_body(const float4& v, int lane, Acc& a,
                                        float2* __restrict__ mycand, int& wcnt) {
    float prev = __shfl_up(v.w, 1);
    if (lane == 0) prev = v.x;   // degenerate (x,x) pair: contributes 0 always

    pair_cls(prev, v.x, a, mycand, wcnt);
    pair_cls(v.x, v.y, a, mycand, wcnt);
    pair_cls(v.y, v.z, a, mycand, wcnt);
    pair_cls(v.z, v.w, a, mycand, wcnt);

    float e0 = v.x, e1 = v.y, e2 = v.z, e3 = v.w;
    a.s1 += e0 + e1 + e2 + e3;
    a.s2 = fmaf(e0, e0, a.s2); a.s2 = fmaf(e1, e1, a.s2);
    a.s2 = fmaf(e2, e2, a.s2); a.s2 = fmaf(e3, e3, a.s2);
    a.s3 = fmaf(e0 * e0, e0, a.s3); a.s3 = fmaf(e1 * e1, e1, a.s3);
    a.s3 = fmaf(e2 * e2, e2, a.s3); a.s3 = fmaf(e3 * e3, e3, a.s3);
    a.s4 = fmaf(e0 * e0, e0 * e0, a.s4); a.s4 = fmaf(e1 * e1, e1 * e1, a.s4);
    a.s4 = fmaf(e2 * e2, e2 * e2, a.s4); a.s4 = fmaf(e3 * e3, e3 * e3, a.s4);
    float a0 = fabsf(e0), a1 = fabsf(e1), a2 = fabsf(e2), a3 = fabsf(e3);
    a.sa += a0 + a1 + a2 + a3;
    a.ss += __builtin_amdgcn_sqrtf(a0) + __builtin_amdgcn_sqrtf(a1)
          + __builtin_amdgcn_sqrtf(a2) + __builtin_amdgcn_sqrtf(a3);
    a.mx = fmaxf(fmaxf(a.mx, e0), fmaxf(e1, fmaxf(e2, e3)));
    a.mn = fminf(fminf(a.mn, e0), fminf(e1, fminf(e2, e3)));
}

// Fallback-only (candidate overflow or |mean| >= B; statistically never):
// exact global re-read computing BOTH zero- and mean-crossings.
__device__ __forceinline__ void p2f(const float4& v, int lane, float m,
                                    int& mc, int& zc) {
    float prev = __shfl_up(v.w, 1);
    if (lane == 0) prev = v.x;
    bool spm = prev < m, szp = prev < 0.f;
    bool m0 = v.x < m, m1 = v.y < m, m2 = v.z < m, m3 = v.w < m;
    bool z0 = v.x < 0.f, z1 = v.y < 0.f, z2 = v.z < 0.f, z3 = v.w < 0.f;
    mc += (int)(spm != m0) + (int)(m0 != m1) + (int)(m1 != m2) + (int)(m2 != m3);
    zc += (int)(szp != z0) + (int)(z0 != z1) + (int)(z1 != z2) + (int)(z2 != z3);
}

// One block per row, SINGLE data pass. Both crossing counts (0-level and
// mean-level) resolved from one LDS candidate list after the mean is known.
__global__ __launch_bounds__(TPB) void stat_feat_fused(const float* __restrict__ x,
                                                       float* __restrict__ out) {
    const int row  = blockIdx.x;
    const int tid  = threadIdx.x;
    const int lane = tid & 63;
    const int wave = tid >> 6;

    const float4* __restrict__ xv = (const float4*)(x + (size_t)row * T_LEN);

    __shared__ float  l[10][NWAVES];
    __shared__ float  s_mean;
    __shared__ float  wlast[NB];   // v.w of vectors with (vi&63)==63, slot vi>>6
    __shared__ float  xfirst[NB];  // v.x of vectors with (vi&63)==0,  slot vi>>6
    __shared__ float2 cand[NWAVES * WCAP];   // 48 KB, per-wave private slices
    __shared__ int    wc[NWAVES];

    float2* __restrict__ mycand = cand + wave * WCAP;
    int wcnt = 0;                 // wave-uniform running candidate count

    Acc a;
    a.s1 = a.s2 = a.s3 = a.s4 = a.sa = a.ss = 0.f;
    a.mx = -__builtin_inff();
    a.mn = __builtin_inff();
    a.mcb = 0;

    for (int g = 0; g < NSUPER; ++g) {
        const int base = g * 4 * TPB + tid;
        const int ia = base, ib = base + TPB, ic = base + 2 * TPB, id = base + 3 * TPB;
        float4 va = xv[ia];      // 4 independent loads in flight
        float4 vb = xv[ib];
        float4 vc = xv[ic];
        float4 vd = xv[id];
        if (lane == 63) {        // stash wave-edge boundary values
            wlast[ia >> 6] = va.w; wlast[ib >> 6] = vb.w;
            wlast[ic >> 6] = vc.w; wlast[id >> 6] = vd.w;
        }
        if (lane == 0) {
            xfirst[ia >> 6] = va.x; xfirst[ib >> 6] = vb.x;
            xfirst[ic >> 6] = vc.x; xfirst[id >> 6] = vd.x;
        }
        p1_body(va, lane, a, mycand, wcnt);
        p1_body(vb, lane, a, mycand, wcnt);
        p1_body(vc, lane, a, mycand, wcnt);
        p1_body(vd, lane, a, mycand, wcnt);
    }

#pragma unroll
    for (int o = 32; o > 0; o >>= 1) {
        a.s1 += __shfl_down(a.s1, o);
        a.s2 += __shfl_down(a.s2, o);
        a.s3 += __shfl_down(a.s3, o);
        a.s4 += __shfl_down(a.s4, o);
        a.sa += __shfl_down(a.sa, o);
        a.ss += __shfl_down(a.ss, o);
        a.mcb += __shfl_down(a.mcb, o);
        a.mx = fmaxf(a.mx, __shfl_down(a.mx, o));
        a.mn = fminf(a.mn, __shfl_down(a.mn, o));
    }

    if (lane == 0) {
        l[0][wave] = a.s1; l[1][wave] = a.s2; l[2][wave] = a.s3; l[3][wave] = a.s4;
        l[4][wave] = a.sa; l[5][wave] = a.ss; l[6][wave] = a.mx; l[7][wave] = a.mn;
        l[8][wave] = (float)a.mcb;
        wc[wave] = wcnt;         // wave-uniform
    }
    __syncthreads();

    float S1 = 0.f, S2 = 0.f, S3 = 0.f, S4 = 0.f, SA = 0.f, SS = 0.f, MCB = 0.f;
    float MX = -__builtin_inff(), MN = __builtin_inff();
    if (tid == 0) {
#pragma unroll
        for (int wv = 0; wv < NWAVES; wv++) {
            S1 += l[0][wv]; S2 += l[1][wv]; S3 += l[2][wv]; S4 += l[3][wv];
            SA += l[4][wv]; SS += l[5][wv];
            MX = fmaxf(MX, l[6][wv]); MN = fminf(MN, l[7][wv]);
            MCB += l[8][wv];
        }
        s_mean = S1 / (float)T_LEN;
    }
    __syncthreads();

    // ------------- resolve crossings from the candidate list -------------
    const float m = s_mean;
    const bool fb = (fabsf(m) >= BANDB) | (wc[0] > WCAP) | (wc[1] > WCAP)
                  | (wc[2] > WCAP) | (wc[3] > WCAP);
    int mcc = 0, zcc = 0;
    if (!fb) {
#pragma unroll
        for (int w = 0; w < NWAVES; w++) {
            const int n = wc[w];
            const float2* __restrict__ cw = cand + w * WCAP;
            for (int i = tid; i < n; i += TPB) {
                float2 c = cw[i];
                mcc += (int)((c.x < m) && (c.y >= m));
                zcc += (int)((c.x < 0.f) && (c.y >= 0.f));
            }
        }
    } else {
        // exact global re-read (never expected)
        for (int g = 0; g < NSUPER; ++g) {
            const int base = g * 4 * TPB + tid;
            const int ia = base, ib = base + TPB, ic = base + 2 * TPB, id = base + 3 * TPB;
            float4 va = xv[ia];
            float4 vb = xv[ib];
            float4 vc = xv[ic];
            float4 vd = xv[id];
            p2f(va, lane, m, mcc, zcc);
            p2f(vb, lane, m, mcc, zcc);
            p2f(vc, lane, m, mcc, zcc);
            p2f(vd, lane, m, mcc, zcc);
        }
    }

    // wave-edge boundary pairs (x[256k-1], x[256k]), exact fp32 from LDS
    int mb = 0, zb = 0;
    if (tid > 0) {
        float wl = wlast[tid - 1];
        float xf = xfirst[tid];
        zb = (int)((wl < 0.f) != (xf < 0.f));
        mb = (int)((wl < m) != (xf < m));
    }

#pragma unroll
    for (int o = 32; o > 0; o >>= 1) {
        mcc += __shfl_down(mcc, o);
        zcc += __shfl_down(zcc, o);
        mb  += __shfl_down(mb, o);
        zb  += __shfl_down(zb, o);
    }

    __syncthreads();
    if (lane == 0) {
        l[0][wave] = (float)mcc;
        l[1][wave] = (float)zcc;
        l[2][wave] = (float)mb;
        l[3][wave] = (float)zb;
    }
    __syncthreads();

    if (tid == 0) {
        float MC = 0.f, ZCC = 0.f, MB = 0.f, ZB = 0.f;
#pragma unroll
        for (int wv = 0; wv < NWAVES; wv++) {
            MC += l[0][wv]; ZCC += l[1][wv]; MB += l[2][wv]; ZB += l[3][wv];
        }
        float ZC;
        if (!fb) {
            MC += MCB + MB;      // always-cross pairs + boundary pairs
            ZC  = ZCC + MCB + ZB;
        } else {
            MC += MB;            // fallback recounted everything directly
            ZC  = ZCC + ZB;
        }

        const float Tf = (float)T_LEN;
        float mean = S1 / Tf;
        float sq_mean = S2 / Tf;
        float var = (S2 - S1 * S1 / Tf) / (Tf - 1.f);
        var = fmaxf(var, 0.f);
        float stdv = sqrtf(var);
        float rms = sqrtf(sq_mean);
        float peak = MX, peak_neg = MN;
        float ptp = peak - peak_neg;
        float abs_peak = fabsf(peak);
        float crest = abs_peak / (rms + EPS);
        float mean_abs = SA / Tf;
        float shape = rms / (mean_abs + EPS);
        float impulse = abs_peak / (mean_abs + EPS);
        float sqrt_mean = SS / Tf;
        float clearance = abs_peak / (sqrt_mean * sqrt_mean + EPS);
        float ex3 = S3 / Tf;
        float m3 = ex3 - 3.f * mean * sq_mean + 2.f * mean * mean * mean;
        float m4 = S4 / Tf - 4.f * mean * ex3 + 6.f * mean * mean * sq_mean
                   - 3.f * mean * mean * mean * mean;
        float skew = m3 / (stdv * stdv * stdv + EPS);
        float kurt = m4 / (stdv * stdv * stdv * stdv + EPS) - 3.f;
        float zcr = ZC / (Tf - 1.f);
        float mcr = MC / (Tf - 1.f);
        float margin = abs_peak / (sqrt_mean + EPS);

        float* o = out + (size_t)row * 17;
        o[0] = mean;   o[1] = stdv;     o[2] = var;        o[3] = rms;
        o[4] = peak;   o[5] = peak_neg; o[6] = ptp;        o[7] = crest;
        o[8] = shape;  o[9] = impulse;  o[10] = clearance; o[11] = skew;
        o[12] = kurt;  o[13] = zcr;     o[14] = mcr;       o[15] = margin;
        o[16] = S2;
    }
}

extern "C" void kernel_launch(void* const* d_in, const int* in_sizes, int n_in,
                              void* d_out, int out_size, void* d_ws, size_t ws_size,
                              hipStream_t stream) {
    const float* x = (const float*)d_in[0];
    float* out = (float*)d_out;
    const int rows = in_sizes[0] / T_LEN;   // 1024
    stat_feat_fused<<<dim3(rows), dim3(TPB), 0, stream>>>(x, out);
}

// Round 5
// 365.960 us; speedup vs baseline: 1.0630x; 1.0415x over previous
//
#include <hip/hip_runtime.h>
#include <math.h>

#define T_LEN  65536
#define TPB    256
#define VECS   (T_LEN / 4)       // 16384 float4 per row
#define VPT    (VECS / TPB)      // 64 vectors per thread
#define NSUPER (VPT / 4)         // 16 super-iterations of 4 loads
#define NWAVES (TPB / 64)        // 4
#define NB     (VECS / 64)       // 256 lane-boundary slots per row
#define EPS    1e-8f

// Mean-crossing candidate band. Row mean of 65536 iid N(0,1) has sd 1/256;
// max |mean| over 1024 rows ~ 0.013. B = 0.025 is ~6.4 sd; if |mean| >= B
// we take the exact global-re-read fallback, so correctness never depends
// on this bound. Smaller band => fewer candidates => 29 KB LDS => 4+
// blocks/CU => the whole 1024-block grid is co-resident (no tail round).
#define BANDB  0.025f
#define WCAP   832               // per-wave slice; expected ~650, sd ~25
#define DUMPO  (NWAVES * WCAP)   // dump region: 64 slots/wave for non-stash

struct Acc { float s1, s2, s3, s4, sa, ss, mx, mn; };

__device__ __forceinline__ int mbcnt64(unsigned long long m) {
    int c = __builtin_amdgcn_mbcnt_lo((unsigned)m, 0);
    return __builtin_amdgcn_mbcnt_hi((unsigned)(m >> 32), c);
}

// Branch-free pair classification. Every pair does ONE unconditional
// ds_write_b64; the address is cndmask'd between the wave's compacted
// candidate slot and a per-lane dump slot. No exec-mask save/restore.
// Bookkeeping (wcnt, wmcb) is wave-uniform via ballot+popcount.
__device__ __forceinline__ void pair_one(float p, float q,
                                         bool pbel, bool pabv, bool pinb,
                                         bool qbel, bool qabv, bool qinb,
                                         float2* __restrict__ cand, int wbase,
                                         int dumpidx, int& wcnt, int& wmcb) {
    bool always = (pbel & qabv) | (pabv & qbel);   // crosses every |m| < B
    wmcb += __builtin_popcountll(__ballot(always));
    bool st = pinb | qinb;                          // >=1 endpoint in band
    unsigned long long mask = __ballot(st);
    int o = wcnt + mbcnt64(mask);
    int idx = (st && (o < WCAP)) ? (wbase + o) : dumpidx;
    cand[idx] = make_float2(fminf(p, q), fmaxf(p, q));
    wcnt += __builtin_popcountll(mask);
}

__device__ __forceinline__ void p1_body(const float4& v, float prev, Acc& a,
                                        float2* __restrict__ cand, int wbase,
                                        int dumpidx, int& wcnt, int& wmcb) {
    // per-element band classes (shared across adjacent pairs)
    bool pb = prev < -BANDB, pa = prev >= BANDB, pi = !(pb | pa);
    bool b0 = v.x < -BANDB, a0 = v.x >= BANDB, i0 = !(b0 | a0);
    bool b1 = v.y < -BANDB, a1 = v.y >= BANDB, i1 = !(b1 | a1);
    bool b2 = v.z < -BANDB, a2 = v.z >= BANDB, i2 = !(b2 | a2);
    bool b3 = v.w < -BANDB, a3 = v.w >= BANDB, i3 = !(b3 | a3);

    pair_one(prev, v.x, pb, pa, pi, b0, a0, i0, cand, wbase, dumpidx, wcnt, wmcb);
    pair_one(v.x, v.y, b0, a0, i0, b1, a1, i1, cand, wbase, dumpidx, wcnt, wmcb);
    pair_one(v.y, v.z, b1, a1, i1, b2, a2, i2, cand, wbase, dumpidx, wcnt, wmcb);
    pair_one(v.z, v.w, b2, a2, i2, b3, a3, i3, cand, wbase, dumpidx, wcnt, wmcb);

    float e0 = v.x, e1 = v.y, e2 = v.z, e3 = v.w;
    a.s1 += e0 + e1 + e2 + e3;
    a.s2 = fmaf(e0, e0, a.s2); a.s2 = fmaf(e1, e1, a.s2);
    a.s2 = fmaf(e2, e2, a.s2); a.s2 = fmaf(e3, e3, a.s2);
    a.s3 = fmaf(e0 * e0, e0, a.s3); a.s3 = fmaf(e1 * e1, e1, a.s3);
    a.s3 = fmaf(e2 * e2, e2, a.s3); a.s3 = fmaf(e3 * e3, e3, a.s3);
    a.s4 = fmaf(e0 * e0, e0 * e0, a.s4); a.s4 = fmaf(e1 * e1, e1 * e1, a.s4);
    a.s4 = fmaf(e2 * e2, e2 * e2, a.s4); a.s4 = fmaf(e3 * e3, e3 * e3, a.s4);
    float a0f = fabsf(e0), a1f = fabsf(e1), a2f = fabsf(e2), a3f = fabsf(e3);
    a.sa += a0f + a1f + a2f + a3f;
    a.ss += __builtin_amdgcn_sqrtf(a0f) + __builtin_amdgcn_sqrtf(a1f)
          + __builtin_amdgcn_sqrtf(a2f) + __builtin_amdgcn_sqrtf(a3f);
    a.mx = fmaxf(fmaxf(a.mx, e0), fmaxf(e1, fmaxf(e2, e3)));
    a.mn = fminf(fminf(a.mn, e0), fminf(e1, fminf(e2, e3)));
}

// Fallback-only (candidate overflow or |mean| >= B; statistically never):
// exact global re-read computing BOTH zero- and mean-crossings.
__device__ __forceinline__ void p2f(const float4& v, int lane, float m,
                                    int& mc, int& zc) {
    float prev = __shfl_up(v.w, 1);
    if (lane == 0) prev = v.x;
    bool spm = prev < m, szp = prev < 0.f;
    bool m0 = v.x < m, m1 = v.y < m, m2 = v.z < m, m3 = v.w < m;
    bool z0 = v.x < 0.f, z1 = v.y < 0.f, z2 = v.z < 0.f, z3 = v.w < 0.f;
    mc += (int)(spm != m0) + (int)(m0 != m1) + (int)(m1 != m2) + (int)(m2 != m3);
    zc += (int)(szp != z0) + (int)(z0 != z1) + (int)(z1 != z2) + (int)(z2 != z3);
}

__global__ __launch_bounds__(TPB) void stat_feat_fused(const float* __restrict__ x,
                                                       float* __restrict__ out) {
    const int row  = blockIdx.x;
    const int tid  = threadIdx.x;
    const int lane = tid & 63;
    const int wave = tid >> 6;

    const float4* __restrict__ xv = (const float4*)(x + (size_t)row * T_LEN);

    __shared__ float  l[10][NWAVES];
    __shared__ float  s_mean;
    __shared__ float  wlast[NB];   // v.w of vecs with (vi&63)==63, slot vi>>6
    __shared__ float  xfirst[NB];  // v.x of vecs with (vi&63)==0,  slot vi>>6
    __shared__ float2 cand[DUMPO + NWAVES * 64];  // 28.7 KB: slices + dump
    __shared__ int    wc[NWAVES];

    const int wbase   = wave * WCAP;
    const int dumpidx = DUMPO + wave * 64 + lane;
    int wcnt = 0;                 // wave-uniform running candidate count
    int wmcb = 0;                 // wave-uniform always-cross count

    Acc a;
    a.s1 = a.s2 = a.s3 = a.s4 = a.sa = a.ss = 0.f;
    a.mx = -__builtin_inff();
    a.mn = __builtin_inff();

    // software pipeline: group g in regs while group g+1 loads are in flight
    float4 c0 = xv[tid], c1 = xv[tid + TPB], c2 = xv[tid + 2 * TPB],
           c3 = xv[tid + 3 * TPB];

    for (int g = 0; g < NSUPER; ++g) {
        const int gn = (g + 1 < NSUPER) ? g + 1 : g;     // last iter: reload (L1)
        const int nbs = gn * 4 * TPB + tid;
        float4 n0 = xv[nbs], n1 = xv[nbs + TPB], n2 = xv[nbs + 2 * TPB],
               n3 = xv[nbs + 3 * TPB];

        const int ia = g * 4 * TPB + tid, ib = ia + TPB,
                  ic = ia + 2 * TPB, id = ia + 3 * TPB;
        if (lane == 63) {        // stash wave-edge boundary values
            wlast[ia >> 6] = c0.w; wlast[ib >> 6] = c1.w;
            wlast[ic >> 6] = c2.w; wlast[id >> 6] = c3.w;
        }
        if (lane == 0) {
            xfirst[ia >> 6] = c0.x; xfirst[ib >> 6] = c1.x;
            xfirst[ic >> 6] = c2.x; xfirst[id >> 6] = c3.x;
        }

        // batch the 4 cross-lane prevs so their DS latency overlaps
        float p0 = __shfl_up(c0.w, 1);
        float p1 = __shfl_up(c1.w, 1);
        float p2 = __shfl_up(c2.w, 1);
        float p3 = __shfl_up(c3.w, 1);
        if (lane == 0) { p0 = c0.x; p1 = c1.x; p2 = c2.x; p3 = c3.x; }

        p1_body(c0, p0, a, cand, wbase, dumpidx, wcnt, wmcb);
        p1_body(c1, p1, a, cand, wbase, dumpidx, wcnt, wmcb);
        p1_body(c2, p2, a, cand, wbase, dumpidx, wcnt, wmcb);
        p1_body(c3, p3, a, cand, wbase, dumpidx, wcnt, wmcb);

        c0 = n0; c1 = n1; c2 = n2; c3 = n3;
    }

#pragma unroll
    for (int o = 32; o > 0; o >>= 1) {
        a.s1 += __shfl_down(a.s1, o);
        a.s2 += __shfl_down(a.s2, o);
        a.s3 += __shfl_down(a.s3, o);
        a.s4 += __shfl_down(a.s4, o);
        a.sa += __shfl_down(a.sa, o);
        a.ss += __shfl_down(a.ss, o);
        a.mx = fmaxf(a.mx, __shfl_down(a.mx, o));
        a.mn = fminf(a.mn, __shfl_down(a.mn, o));
    }

    if (lane == 0) {
        l[0][wave] = a.s1; l[1][wave] = a.s2; l[2][wave] = a.s3; l[3][wave] = a.s4;
        l[4][wave] = a.sa; l[5][wave] = a.ss; l[6][wave] = a.mx; l[7][wave] = a.mn;
        l[8][wave] = (float)wmcb;          // wave-uniform, no reduction needed
        wc[wave] = wcnt;
    }
    __syncthreads();

    float S1 = 0.f, S2 = 0.f, S3 = 0.f, S4 = 0.f, SA = 0.f, SS = 0.f, MCB = 0.f;
    float MX = -__builtin_inff(), MN = __builtin_inff();
    if (tid == 0) {
#pragma unroll
        for (int wv = 0; wv < NWAVES; wv++) {
            S1 += l[0][wv]; S2 += l[1][wv]; S3 += l[2][wv]; S4 += l[3][wv];
            SA += l[4][wv]; SS += l[5][wv];
            MX = fmaxf(MX, l[6][wv]); MN = fminf(MN, l[7][wv]);
            MCB += l[8][wv];
        }
        s_mean = S1 / (float)T_LEN;
    }
    __syncthreads();

    // ------------- resolve crossings from the candidate list -------------
    const float m = s_mean;
    const bool fb = (fabsf(m) >= BANDB) | (wc[0] > WCAP) | (wc[1] > WCAP)
                  | (wc[2] > WCAP) | (wc[3] > WCAP);
    int mcc = 0, zcc = 0;
    if (!fb) {
#pragma unroll
        for (int w = 0; w < NWAVES; w++) {
            const int n = wc[w];
            const float2* __restrict__ cw = cand + w * WCAP;
            for (int i = tid; i < n; i += TPB) {
                float2 c = cw[i];
                mcc += (int)((c.x < m) && (c.y >= m));
                zcc += (int)((c.x < 0.f) && (c.y >= 0.f));
            }
        }
    } else {
        for (int g = 0; g < NSUPER; ++g) {
            const int base = g * 4 * TPB + tid;
            float4 va = xv[base];
            float4 vb = xv[base + TPB];
            float4 vc = xv[base + 2 * TPB];
            float4 vd = xv[base + 3 * TPB];
            p2f(va, lane, m, mcc, zcc);
            p2f(vb, lane, m, mcc, zcc);
            p2f(vc, lane, m, mcc, zcc);
            p2f(vd, lane, m, mcc, zcc);
        }
    }

    // wave-edge boundary pairs (x[256k-1], x[256k]), exact fp32 from LDS
    int mb = 0, zb = 0;
    if (tid > 0) {
        float wl = wlast[tid - 1];
        float xf = xfirst[tid];
        zb = (int)((wl < 0.f) != (xf < 0.f));
        mb = (int)((wl < m) != (xf < m));
    }

#pragma unroll
    for (int o = 32; o > 0; o >>= 1) {
        mcc += __shfl_down(mcc, o);
        zcc += __shfl_down(zcc, o);
        mb  += __shfl_down(mb, o);
        zb  += __shfl_down(zb, o);
    }

    __syncthreads();
    if (lane == 0) {
        l[0][wave] = (float)mcc;
        l[1][wave] = (float)zcc;
        l[2][wave] = (float)mb;
        l[3][wave] = (float)zb;
    }
    __syncthreads();

    if (tid == 0) {
        float MC = 0.f, ZCC = 0.f, MB = 0.f, ZB = 0.f;
#pragma unroll
        for (int wv = 0; wv < NWAVES; wv++) {
            MC += l[0][wv]; ZCC += l[1][wv]; MB += l[2][wv]; ZB += l[3][wv];
        }
        float ZC;
        if (!fb) {
            MC += MCB + MB;      // always-cross pairs + boundary pairs
            ZC  = ZCC + MCB + ZB;
        } else {
            MC += MB;            // fallback recounted everything directly
            ZC  = ZCC + ZB;
        }

        const float Tf = (float)T_LEN;
        float mean = S1 / Tf;
        float sq_mean = S2 / Tf;
        float var = (S2 - S1 * S1 / Tf) / (Tf - 1.f);
        var = fmaxf(var, 0.f);
        float stdv = sqrtf(var);
        float rms = sqrtf(sq_mean);
        float peak = MX, peak_neg = MN;
        float ptp = peak - peak_neg;
        float abs_peak = fabsf(peak);
        float crest = abs_peak / (rms + EPS);
        float mean_abs = SA / Tf;
        float shape = rms / (mean_abs + EPS);
        float impulse = abs_peak / (mean_abs + EPS);
        float sqrt_mean = SS / Tf;
        float clearance = abs_peak / (sqrt_mean * sqrt_mean + EPS);
        float ex3 = S3 / Tf;
        float m3 = ex3 - 3.f * mean * sq_mean + 2.f * mean * mean * mean;
        float m4 = S4 / Tf - 4.f * mean * ex3 + 6.f * mean * mean * sq_mean
                   - 3.f * mean * mean * mean * mean;
        float skew = m3 / (stdv * stdv * stdv + EPS);
        float kurt = m4 / (stdv * stdv * stdv * stdv + EPS) - 3.f;
        float zcr = ZC / (Tf - 1.f);
        float mcr = MC / (Tf - 1.f);
        float margin = abs_peak / (sqrt_mean + EPS);

        float* o = out + (size_t)row * 17;
        o[0] = mean;   o[1] = stdv;     o[2] = var;        o[3] = rms;
        o[4] = peak;   o[5] = peak_neg; o[6] = ptp;        o[7] = crest;
        o[8] = shape;  o[9] = impulse;  o[10] = clearance; o[11] = skew;
        o[12] = kurt;  o[13] = zcr;     o[14] = mcr;       o[15] = margin;
        o[16] = S2;
    }
}

extern "C" void kernel_launch(void* const* d_in, const int* in_sizes, int n_in,
                              void* d_out, int out_size, void* d_ws, size_t ws_size,
                              hipStream_t stream) {
    const float* x = (const float*)d_in[0];
    float* out = (float*)d_out;
    const int rows = in_sizes[0] / T_LEN;   // 1024
    stat_feat_fused<<<dim3(rows), dim3(TPB), 0, stream>>>(x, out);
}